// Round 4
// baseline (685.078 us; speedup 1.0000x reference)
//
#include <hip/hip_runtime.h>
#include <stdint.h>

typedef unsigned short u16;
typedef __attribute__((ext_vector_type(8))) short bf16x8;
typedef __attribute__((ext_vector_type(4))) float f32x4;

#define AS1C(p) ((const __attribute__((address_space(1))) char*)(const char*)(p))
#define AS3C(p) ((__attribute__((address_space(3))) char*)(char*)(p))

static __device__ __forceinline__ u16 f2bf(float f) {
  uint32_t u = __builtin_bit_cast(uint32_t, f);
  u = (u + 0x7FFFu + ((u >> 16) & 1u)) >> 16;
  return (u16)u;
}

// ---------------- fp32 -> bf16 conversion ----------------
__global__ __launch_bounds__(256) void k_f2bf(const float* __restrict__ src,
                                              u16* __restrict__ dst, int n4) {
  int i = blockIdx.x * blockDim.x + threadIdx.x;
  if (i >= n4) return;
  float4 v = reinterpret_cast<const float4*>(src)[i];
  ushort4 o;
  o.x = f2bf(v.x); o.y = f2bf(v.y); o.z = f2bf(v.z); o.w = f2bf(v.w);
  reinterpret_cast<ushort4*>(dst)[i] = o;
}

// =============== 256x256 GEMM, BK=32, 3-buffer, 1 barrier/K-tile ===============
// C[M,N] = act(A[M,K] * B[N,K]^T + bias).  8 waves (2M x 4N), per-wave 128x64.
// LDS 96KB = 3 bufs x (A 16KB + B 16KB). Stage tile t+2 during iter t
// (counted vmcnt(4) gate), single s_barrier per iter -> waves skew so LDS
// reads overlap MFMA across waves. XOR swizzle: phys_chunk = c ^ (row&3).
template<bool OUT_BF16, bool RELU>
__global__ __launch_bounds__(512, 2) void k_gemm256(const u16* __restrict__ A,
                                                    const u16* __restrict__ B,
                                                    const float* __restrict__ bias,
                                                    void* __restrict__ C,
                                                    int M, int N, int K) {
  __shared__ __align__(16) char lds[98304];
  const int tid = threadIdx.x, lane = tid & 63, wid = tid >> 6;
  const int wm = wid >> 2, wn = wid & 3;

  // T1: XCD-aware block swizzle (grid % 8 == 0 for all our shapes)
  const int nbx = N >> 8;
  const int cpx = gridDim.x >> 3;
  const int sid = ((int)blockIdx.x & 7) * cpx + ((int)blockIdx.x >> 3);
  const int bm = (sid / nbx) << 8;
  const int bn = (sid % nbx) << 8;

  // staging geometry: tile (A or B) = 256 rows x 64B; per wave 2KB (2 loads) each
  int ga[2], gb[2];
  unsigned wdst[2];
#pragma unroll
  for (int c = 0; c < 2; ++c) {
    const int o = wid * 2048 + c * 1024 + lane * 16;   // linear offset in 16KB tile
    const int r = o >> 6;                              // row 0..255
    const int kb = (((o >> 4) & 3) ^ (r & 3)) * 16;    // inverse-swizzled k-byte
    ga[c] = (bm + r) * K * 2 + kb;
    gb[c] = (bn + r) * K * 2 + kb;
    wdst[c] = (unsigned)__builtin_amdgcn_readfirstlane(wid * 2048 + c * 1024);
  }
  const char* Ag = (const char*)A;
  const char* Bg = (const char*)B;

  // fragment read offsets: row*64 + (chunk ^ (row&3))*16, chunk = lane>>4
  const int arow = wm * 128 + (lane & 15);
  const int brow = wn * 64 + (lane & 15);
  const int ckA = ((lane >> 4) ^ (arow & 3)) * 16;     // arow&3 == lane&3
  const int ckB = ((lane >> 4) ^ (brow & 3)) * 16;

  f32x4 acc[8][4];
#pragma unroll
  for (int m = 0; m < 8; ++m)
#pragma unroll
    for (int n = 0; n < 4; ++n) acc[m][n] = 0.f;
  bf16x8 am[8], bfr[4];

#define STG(t, b) do { \
  const int koff_ = (t) * 64; \
  _Pragma("unroll") for (int c_ = 0; c_ < 2; ++c_) { \
    __builtin_amdgcn_global_load_lds(AS1C(Ag + ga[c_] + koff_), \
        AS3C(lds + ((b) * 32768 + wdst[c_])), 16, 0, 0); \
    __builtin_amdgcn_global_load_lds(AS1C(Bg + gb[c_] + koff_), \
        AS3C(lds + ((b) * 32768 + 16384 + wdst[c_])), 16, 0, 0); \
  } } while (0)

#define MM(mh) do { \
  __builtin_amdgcn_s_setprio(1); \
  _Pragma("unroll") for (int m_ = 0; m_ < 4; ++m_) \
  _Pragma("unroll") for (int n_ = 0; n_ < 4; ++n_) \
    acc[(mh) * 4 + m_][n_] = __builtin_amdgcn_mfma_f32_16x16x32_bf16( \
        am[(mh) * 4 + m_], bfr[n_], acc[(mh) * 4 + m_][n_], 0, 0, 0); \
  __builtin_amdgcn_s_setprio(0); } while (0)

  const int nT = K >> 5, tmask = nT - 1;

  // prologue: tiles 0,1 -> bufs 0,1; wait tile0 (4 oldest of 8)
  STG(0, 0); STG(1, 1);
  asm volatile("s_waitcnt vmcnt(4)" ::: "memory");
  __builtin_amdgcn_sched_barrier(0);
  __builtin_amdgcn_s_barrier();

  int bR = 0;
  for (int t = 0; t < nT; ++t) {
    const int bW = (bR >= 1) ? bR - 1 : 2;   // (bR+2)%3
    const int base = bR * 32768;
    // first 8 reads: A-frags 0..3 + all B-frags
#pragma unroll
    for (int m_ = 0; m_ < 4; ++m_)
      am[m_] = *(const bf16x8*)(lds + base + (arow + m_ * 16) * 64 + ckA);
#pragma unroll
    for (int n_ = 0; n_ < 4; ++n_)
      bfr[n_] = *(const bf16x8*)(lds + base + 16384 + (brow + n_ * 16) * 64 + ckB);
    // last 4 reads: A-frags 4..7
#pragma unroll
    for (int m_ = 4; m_ < 8; ++m_)
      am[m_] = *(const bf16x8*)(lds + base + (arow + m_ * 16) * 64 + ckA);
    // stage tile t+2 into freed buffer
    STG((t + 2) & tmask, bW);
    // first half compute once first 8 reads land
    asm volatile("s_waitcnt lgkmcnt(4)" ::: "memory");
    __builtin_amdgcn_sched_barrier(0);
    MM(0);
    asm volatile("s_waitcnt lgkmcnt(0)" ::: "memory");
    __builtin_amdgcn_sched_barrier(0);
    MM(1);
    // gate: tile t+1 resident (4 oldest of <=8 outstanding)
    asm volatile("s_waitcnt vmcnt(4)" ::: "memory");
    __builtin_amdgcn_sched_barrier(0);
    __builtin_amdgcn_s_barrier();
    bR = (bR == 2) ? 0 : bR + 1;
  }
  asm volatile("s_waitcnt vmcnt(0)" ::: "memory");

  // epilogue
  u16* Cb = (u16*)C;
  float* Cf = (float*)C;
#pragma unroll
  for (int n = 0; n < 4; ++n) {
    const int col = bn + wn * 64 + n * 16 + (lane & 15);
    const float bv = bias[col];
#pragma unroll
    for (int m = 0; m < 8; ++m) {
      const int rbase = bm + wm * 128 + m * 16 + (lane >> 4) * 4;
#pragma unroll
      for (int q = 0; q < 4; ++q) {
        float v = acc[m][n][q] + bv;
        if (RELU) v = fmaxf(v, 0.f);
        const long idx = (long)(rbase + q) * N + col;
        if (OUT_BF16) Cb[idx] = f2bf(v);
        else          Cf[idx] = v;
      }
    }
  }
#undef STG
#undef MM
}

// ---------------- V transpose: qkv V-block -> vt[g][h][c(64)][n(512)] ----------------
__global__ __launch_bounds__(256) void k_transpose_v(const u16* __restrict__ qkv,
                                                     u16* __restrict__ vt) {
  const int gh = blockIdx.x, g = gh >> 4, h = gh & 15;
  const int tid = threadIdx.x;
  __shared__ __align__(16) u16 tile[4096]; // [n(64)][c(64)] chunk-swizzled
  for (int nt = 0; nt < 8; ++nt) {
    const int n0 = nt * 64;
#pragma unroll
    for (int c = 0; c < 2; ++c) {
      const int ch = tid * 2 + c;           // 0..511
      const int n = ch >> 3;                // 0..63
      const int cc = ch & 7;                // logical 8-elem chunk in c-dim
      const uint4 v = *reinterpret_cast<const uint4*>(
          qkv + (long)(g * 512 + n0 + n) * 3072 + 2048 + h * 64 + cc * 8);
      const int phys = cc ^ (n & 7) ^ (n >> 3);
      *reinterpret_cast<uint4*>(tile + n * 64 + phys * 8) = v;
    }
    __syncthreads();
#pragma unroll
    for (int c = 0; c < 2; ++c) {
      const int ch = tid * 2 + c;
      const int crow = ch >> 3;             // head-col index 0..63
      const int noff = (ch & 7) * 8;
      union { u16 s[8]; uint4 u; } val;
#pragma unroll
      for (int i = 0; i < 8; ++i) {
        const int n = noff + i;
        const int phys = (crow >> 3) ^ (n & 7) ^ (n >> 3);
        val.s[i] = tile[n * 64 + phys * 8 + (crow & 7)];
      }
      *reinterpret_cast<uint4*>(vt + (long)(gh * 64 + crow) * 512 + n0 + noff) = val.u;
    }
    __syncthreads();
  }
}

// ---------------- fused attention ----------------
// grid: (8 q-blocks, 16 heads, 32 graphs), 256 threads (4 waves x 16 Q rows)
__global__ __launch_bounds__(256) void k_attn(const u16* __restrict__ qkv,
                                              const u16* __restrict__ vt,
                                              u16* __restrict__ out) {
  __shared__ __align__(16) char Ks[8192];       // [kvrow(64)][128B], chunk-XOR swizzled
  __shared__ __align__(16) char Vs[8192];       // [c(64)][128B kv], chunk-XOR swizzled
  __shared__ __align__(16) char Ps[4][2048];    // per-wave P [16][128B], swizzled
  const int tid = threadIdx.x, lane = tid & 63, wid = tid >> 6;
  const int qb = blockIdx.x, h = blockIdx.y, g = blockIdx.z;
  const int gh = g * 16 + h;
  const long grow0 = (long)g * 512;
  const char* qbase = (const char*)qkv;

  // Q fragments (row = lane&15 of this wave's 16-row strip)
  const long qrow = qb * 64 + wid * 16 + (lane & 15);
  bf16x8 qf[2];
#pragma unroll
  for (int kf = 0; kf < 2; ++kf) {
    const long go = (((grow0 + qrow) * 3072) + h * 64 + kf * 32 + (lane >> 4) * 8) * 2;
    qf[kf] = *reinterpret_cast<const bf16x8*>(qbase + go);
  }

  f32x4 oacc[4];
#pragma unroll
  for (int i = 0; i < 4; i++) oacc[i] = 0.f;
  float mrun[4], lrun[4];
#pragma unroll
  for (int q = 0; q < 4; q++) { mrun[q] = -3.0e38f; lrun[q] = 0.f; }

  const unsigned l0 = (unsigned)__builtin_amdgcn_readfirstlane(wid * 2048);
  const unsigned l1 = l0 + 1024;

  for (int it = 0; it < 8; ++it) {
    const int kv0 = it * 64;
    // stage K tile and V tile (source-side XOR swizzle, linear LDS dest)
#pragma unroll
    for (int c = 0; c < 2; ++c) {
      const int o = wid * 2048 + c * 1024 + lane * 16;
      const int row = o >> 7;
      const int pch = (o >> 4) & 7;
      const int lch = pch ^ (row & 7);
      const long gK = (((grow0 + kv0 + row) * 3072) + 1024 + h * 64 + lch * 8) * 2;
      __builtin_amdgcn_global_load_lds(AS1C(qbase + gK), AS3C(Ks + (c ? l1 : l0)), 16, 0, 0);
      const long gV = (((long)(gh * 64 + row)) * 512 + kv0 + lch * 8) * 2;
      __builtin_amdgcn_global_load_lds(AS1C((const char*)vt + gV), AS3C(Vs + (c ? l1 : l0)), 16, 0, 0);
    }
    __syncthreads();

    // S = Q K^T / 8  (4 tiles of 16 kv cols)
    f32x4 s[4];
#pragma unroll
    for (int nt = 0; nt < 4; ++nt) {
      const int krow = nt * 16 + (lane & 15);
      const int sw = krow & 7;
      const bf16x8 k0 = *reinterpret_cast<const bf16x8*>(Ks + krow * 128 + (((lane >> 4)) ^ sw) * 16);
      const bf16x8 k1 = *reinterpret_cast<const bf16x8*>(Ks + krow * 128 + (((lane >> 4) + 4) ^ sw) * 16);
      f32x4 t = 0.f;
      t = __builtin_amdgcn_mfma_f32_16x16x32_bf16(qf[0], k0, t, 0, 0, 0);
      t = __builtin_amdgcn_mfma_f32_16x16x32_bf16(qf[1], k1, t, 0, 0, 0);
#pragma unroll
      for (int q = 0; q < 4; q++) t[q] *= 0.125f;
      s[nt] = t;
    }

    // online softmax update (rows owned: (lane>>4)*4+q; cols across 16 lanes)
    float tmax[4];
#pragma unroll
    for (int q = 0; q < 4; q++)
      tmax[q] = fmaxf(fmaxf(s[0][q], s[1][q]), fmaxf(s[2][q], s[3][q]));
#pragma unroll
    for (int d = 1; d < 16; d <<= 1)
#pragma unroll
      for (int q = 0; q < 4; q++) tmax[q] = fmaxf(tmax[q], __shfl_xor(tmax[q], d));
    float sf[4];
#pragma unroll
    for (int q = 0; q < 4; q++) {
      const float mn = fmaxf(mrun[q], tmax[q]);
      sf[q] = __expf(mrun[q] - mn);
      mrun[q] = mn;
    }
    float rs[4] = {0.f, 0.f, 0.f, 0.f};
#pragma unroll
    for (int nt = 0; nt < 4; nt++)
#pragma unroll
      for (int q = 0; q < 4; q++) {
        const float p = __expf(s[nt][q] - mrun[q]);
        s[nt][q] = p;
        rs[q] += p;
      }
#pragma unroll
    for (int d = 1; d < 16; d <<= 1)
#pragma unroll
      for (int q = 0; q < 4; q++) rs[q] += __shfl_xor(rs[q], d);
#pragma unroll
    for (int q = 0; q < 4; q++) lrun[q] = lrun[q] * sf[q] + rs[q];
#pragma unroll
    for (int i = 0; i < 4; i++)
#pragma unroll
      for (int q = 0; q < 4; q++) oacc[i][q] *= sf[q];

    // P (bf16) -> per-wave LDS, swizzled
    char* pw = Ps[wid];
#pragma unroll
    for (int nt = 0; nt < 4; nt++) {
      const int cc = nt * 16 + (lane & 15);
#pragma unroll
      for (int q = 0; q < 4; q++) {
        const int r = (lane >> 4) * 4 + q;
        const int phys = (cc >> 3) ^ (r & 7);
        *(u16*)(pw + r * 128 + phys * 16 + (cc & 7) * 2) = f2bf(s[nt][q]);
      }
    }

    // O += P V
#pragma unroll
    for (int kf = 0; kf < 2; ++kf) {
      const int prow = lane & 15;
      const bf16x8 pa = *reinterpret_cast<const bf16x8*>(
          pw + prow * 128 + ((kf * 4 + (lane >> 4)) ^ (prow & 7)) * 16);
#pragma unroll
      for (int ot = 0; ot < 4; ++ot) {
        const int vr = ot * 16 + (lane & 15);
        const bf16x8 vb = *reinterpret_cast<const bf16x8*>(
            Vs + vr * 128 + ((kf * 4 + (lane >> 4)) ^ (vr & 7)) * 16);
        oacc[ot] = __builtin_amdgcn_mfma_f32_16x16x32_bf16(pa, vb, oacc[ot], 0, 0, 0);
      }
    }
    __syncthreads();
  }

  // epilogue: O / l -> bf16
#pragma unroll
  for (int ot = 0; ot < 4; ++ot) {
    const int col = h * 64 + ot * 16 + (lane & 15);
#pragma unroll
    for (int q = 0; q < 4; q++) {
      const long r = grow0 + qb * 64 + wid * 16 + (lane >> 4) * 4 + q;
      out[r * 1024 + col] = f2bf(oacc[ot][q] / lrun[q]);
    }
  }
}

// ---------------- residual + layernorm ----------------
template<bool EMIT_BF16>
__global__ __launch_bounds__(256) void k_ln(const float* __restrict__ A,
                                            const float* __restrict__ Bz,
                                            const float* __restrict__ gam,
                                            const float* __restrict__ bet,
                                            float* __restrict__ out_f,
                                            u16* __restrict__ out_b) {
  const int row = blockIdx.x;
  const int tid = threadIdx.x;
  const long base = (long)row * 1024;
  const float4 a = reinterpret_cast<const float4*>(A + base)[tid];
  const float4 b = reinterpret_cast<const float4*>(Bz + base)[tid];
  const float x0 = a.x + b.x, x1 = a.y + b.y, x2 = a.z + b.z, x3 = a.w + b.w;
  float s1 = x0 + x1 + x2 + x3;
  float s2 = x0 * x0 + x1 * x1 + x2 * x2 + x3 * x3;
#pragma unroll
  for (int d = 1; d < 64; d <<= 1) { s1 += __shfl_xor(s1, d); s2 += __shfl_xor(s2, d); }
  __shared__ float red[8];
  const int wid = tid >> 6, lane = tid & 63;
  if (lane == 0) { red[wid] = s1; red[4 + wid] = s2; }
  __syncthreads();
  s1 = red[0] + red[1] + red[2] + red[3];
  s2 = red[4] + red[5] + red[6] + red[7];
  const float mu = s1 * (1.f / 1024.f);
  const float var = s2 * (1.f / 1024.f) - mu * mu;
  const float rstd = rsqrtf(var + 1e-5f);
  const float4 gv = reinterpret_cast<const float4*>(gam)[tid];
  const float4 bv = reinterpret_cast<const float4*>(bet)[tid];
  float4 y;
  y.x = (x0 - mu) * rstd * gv.x + bv.x;
  y.y = (x1 - mu) * rstd * gv.y + bv.y;
  y.z = (x2 - mu) * rstd * gv.z + bv.z;
  y.w = (x3 - mu) * rstd * gv.w + bv.w;
  reinterpret_cast<float4*>(out_f + base)[tid] = y;
  if (EMIT_BF16) {
    ushort4 o;
    o.x = f2bf(y.x); o.y = f2bf(y.y); o.z = f2bf(y.z); o.w = f2bf(y.w);
    reinterpret_cast<ushort4*>(out_b + base)[tid] = o;
  }
}

// ---------------- launcher ----------------
extern "C" void kernel_launch(void* const* d_in, const int* in_sizes, int n_in,
                              void* d_out, int out_size, void* d_ws, size_t ws_size,
                              hipStream_t stream) {
  const float* h    = (const float*)d_in[0];
  const float* w_in = (const float*)d_in[1];
  const float* b_in = (const float*)d_in[2];
  const float* w_o  = (const float*)d_in[3];
  const float* b_o  = (const float*)d_in[4];
  const float* ln1g = (const float*)d_in[5];
  const float* ln1b = (const float*)d_in[6];
  const float* ln2g = (const float*)d_in[7];
  const float* ln2b = (const float*)d_in[8];
  const float* w1   = (const float*)d_in[9];
  const float* b1   = (const float*)d_in[10];
  const float* w2   = (const float*)d_in[11];
  const float* b2   = (const float*)d_in[12];

  const size_t WS_NEED = 184549376;
  if (ws_size < WS_NEED) {
    hipMemsetAsync(d_out, 0, (size_t)out_size * 4, stream);
    return;
  }

  char* W = (char*)d_ws;
  u16* h_bf     = (u16*)(W + 0);            // 33554432 B
  u16* w_in_bf  = (u16*)(W + 33554432);     // 6291456 B
  u16* w_out_bf = (u16*)(W + 39845888);     // 2097152 B
  u16* w1_bf    = (u16*)(W + 41943040);     // 4194304 B
  u16* w2_bf    = (u16*)(W + 46137344);     // 4194304 B
  u16* qkv      = (u16*)(W + 50331648);     // 100663296 B (dead after attn)
  u16* vt       = (u16*)(W + 150994944);    // 33554432 B  (dead after attn)
  float* x1     = (float*)(W + 50331648);   // 67108864 B (reuses qkv[0:67MB))
  u16* f1       = (u16*)(W + 117440512);    // 67108864 B (reuses qkv tail + vt)
  u16* attn_bf  = h_bf;
  u16* x1_bf    = h_bf;
  float* o32    = (float*)d_out;
  float* f2     = (float*)d_out;

  // bf16 conversions
  k_f2bf<<<dim3(16384), 256, 0, stream>>>(h, h_bf, 4194304);
  k_f2bf<<<dim3(3072),  256, 0, stream>>>(w_in, w_in_bf, 786432);
  k_f2bf<<<dim3(1024),  256, 0, stream>>>(w_o, w_out_bf, 262144);
  k_f2bf<<<dim3(2048),  256, 0, stream>>>(w1, w1_bf, 524288);
  k_f2bf<<<dim3(2048),  256, 0, stream>>>(w2, w2_bf, 524288);

  // qkv = h @ w_in^T + b_in   [16384, 3072] bf16   grid 64*12=768
  k_gemm256<true, false><<<dim3(768), 512, 0, stream>>>(h_bf, w_in_bf, b_in, (void*)qkv, 16384, 3072, 1024);
  // V transpose for attention B-operand
  k_transpose_v<<<dim3(512), 256, 0, stream>>>(qkv, vt);
  // fused attention -> attn_bf [16384, 1024] bf16
  k_attn<<<dim3(8, 16, 32), 256, 0, stream>>>(qkv, vt, attn_bf);
  // o = attn @ w_out^T + b_out  [16384, 1024] fp32 -> d_out   grid 64*4=256
  k_gemm256<false, false><<<dim3(256), 512, 0, stream>>>(attn_bf, w_out_bf, b_o, (void*)o32, 16384, 1024, 1024);
  // x1 = LN(h + o); also emit x1 as bf16 for FFN
  k_ln<true><<<dim3(16384), 256, 0, stream>>>(h, o32, ln1g, ln1b, x1, x1_bf);
  // f1 = relu(x1 @ w1^T + b1)  [16384, 2048] bf16   grid 64*8=512
  k_gemm256<true, true><<<dim3(512), 512, 0, stream>>>(x1_bf, w1_bf, b1, (void*)f1, 16384, 2048, 1024);
  // f2 = f1 @ w2^T + b2        [16384, 1024] fp32 -> d_out   grid 64*4=256
  k_gemm256<false, false><<<dim3(256), 512, 0, stream>>>(f1, w2_bf, b2, (void*)f2, 16384, 1024, 2048);
  // out = LN(x1 + f2)  (in-place on d_out)
  k_ln<false><<<dim3(16384), 256, 0, stream>>>(x1, f2, ln2g, ln2b, (float*)d_out, (u16*)nullptr);
}

// Round 8
// 668.540 us; speedup vs baseline: 1.0247x; 1.0247x over previous
//
#include <hip/hip_runtime.h>
#include <stdint.h>

typedef unsigned short u16;
typedef __attribute__((ext_vector_type(8))) short bf16x8;
typedef __attribute__((ext_vector_type(4))) float f32x4;

#define AS1C(p) ((const __attribute__((address_space(1))) char*)(const char*)(p))
#define AS3C(p) ((__attribute__((address_space(3))) char*)(char*)(p))

static __device__ __forceinline__ u16 f2bf(float f) {
  uint32_t u = __builtin_bit_cast(uint32_t, f);
  u = (u + 0x7FFFu + ((u >> 16) & 1u)) >> 16;
  return (u16)u;
}

// ---------------- fp32 -> bf16 conversion (all 5 tensors, one launch) ----------------
__global__ __launch_bounds__(256) void k_f2bf5(const float* __restrict__ s0, u16* __restrict__ d0,
                                               const float* __restrict__ s1, u16* __restrict__ d1,
                                               const float* __restrict__ s2, u16* __restrict__ d2,
                                               const float* __restrict__ s3, u16* __restrict__ d3,
                                               const float* __restrict__ s4, u16* __restrict__ d4) {
  const int bid = blockIdx.x;
  const float* s; u16* d; int i;
  if (bid < 16384)      { s = s0; d = d0; i = bid * 256 + threadIdx.x; }
  else if (bid < 19456) { s = s1; d = d1; i = (bid - 16384) * 256 + threadIdx.x; }
  else if (bid < 20480) { s = s2; d = d2; i = (bid - 19456) * 256 + threadIdx.x; }
  else if (bid < 22528) { s = s3; d = d3; i = (bid - 20480) * 256 + threadIdx.x; }
  else                  { s = s4; d = d4; i = (bid - 22528) * 256 + threadIdx.x; }
  float4 v = reinterpret_cast<const float4*>(s)[i];
  ushort4 o;
  o.x = f2bf(v.x); o.y = f2bf(v.y); o.z = f2bf(v.z); o.w = f2bf(v.w);
  reinterpret_cast<ushort4*>(d)[i] = o;
}

// =============== 256x256 GEMM, BK=32, 3-buffer, 1 barrier/K-tile ===============
// Swizzle: phys_chunk = c ^ (r&3) ^ ((r>>2)&3)  (2-way max on ds_read_b128).
// Epilogue: n innermost so each 64B line's 4 segments issue back-to-back.
template<bool OUT_BF16, bool RELU>
__global__ __launch_bounds__(512, 2) void k_gemm256(const u16* __restrict__ A,
                                                    const u16* __restrict__ B,
                                                    const float* __restrict__ bias,
                                                    void* __restrict__ C,
                                                    int M, int N, int K) {
  __shared__ __align__(16) char lds[98304];
  const int tid = threadIdx.x, lane = tid & 63, wid = tid >> 6;
  const int wm = wid >> 2, wn = wid & 3;

  // T1: XCD-aware block swizzle (grid % 8 == 0 for all our shapes)
  const int nbx = N >> 8;
  const int cpx = gridDim.x >> 3;
  const int sid = ((int)blockIdx.x & 7) * cpx + ((int)blockIdx.x >> 3);
  const int bm = (sid / nbx) << 8;
  const int bn = (sid % nbx) << 8;

  // staging: tile (A or B) = 256 rows x 64B; per wave 2KB (2 gload_lds) each
  int ga[2], gb[2];
  unsigned wdst[2];
#pragma unroll
  for (int c = 0; c < 2; ++c) {
    const int o = wid * 2048 + c * 1024 + lane * 16;   // linear offset in 16KB tile
    const int r = o >> 6;                              // row 0..255
    const int c2 = (o >> 4) & 3;                       // physical chunk slot
    const int kb = (c2 ^ (r & 3) ^ ((r >> 2) & 3)) * 16; // inverse-swizzled k-byte
    ga[c] = (bm + r) * K * 2 + kb;
    gb[c] = (bn + r) * K * 2 + kb;
    wdst[c] = (unsigned)__builtin_amdgcn_readfirstlane(wid * 2048 + c * 1024);
  }
  const char* Ag = (const char*)A;
  const char* Bg = (const char*)B;

  // fragment reads: slot = (lane>>4) ^ (row&3) ^ ((row>>2)&3); invariant in frag idx
  const int arow = wm * 128 + (lane & 15);
  const int brow = wn * 64 + (lane & 15);
  const int ck = (((lane >> 4) ^ (lane & 3) ^ ((lane >> 2) & 3)) & 3) * 16;

  f32x4 acc[8][4];
#pragma unroll
  for (int m = 0; m < 8; ++m)
#pragma unroll
    for (int n = 0; n < 4; ++n) acc[m][n] = 0.f;
  bf16x8 am[8], bfr[4];

#define STG(t, b) do { \
  const int koff_ = (t) * 64; \
  _Pragma("unroll") for (int c_ = 0; c_ < 2; ++c_) { \
    __builtin_amdgcn_global_load_lds(AS1C(Ag + ga[c_] + koff_), \
        AS3C(lds + ((b) * 32768 + wdst[c_])), 16, 0, 0); \
    __builtin_amdgcn_global_load_lds(AS1C(Bg + gb[c_] + koff_), \
        AS3C(lds + ((b) * 32768 + 16384 + wdst[c_])), 16, 0, 0); \
  } } while (0)

#define MM(mh) do { \
  __builtin_amdgcn_s_setprio(1); \
  _Pragma("unroll") for (int m_ = 0; m_ < 4; ++m_) \
  _Pragma("unroll") for (int n_ = 0; n_ < 4; ++n_) \
    acc[(mh) * 4 + m_][n_] = __builtin_amdgcn_mfma_f32_16x16x32_bf16( \
        am[(mh) * 4 + m_], bfr[n_], acc[(mh) * 4 + m_][n_], 0, 0, 0); \
  __builtin_amdgcn_s_setprio(0); } while (0)

  const int nT = K >> 5, tmask = nT - 1;

  // prologue: tiles 0,1 -> bufs 0,1; wait tile0 (4 oldest of 8)
  STG(0, 0); STG(1, 1);
  asm volatile("s_waitcnt vmcnt(4)" ::: "memory");
  __builtin_amdgcn_sched_barrier(0);
  __builtin_amdgcn_s_barrier();

  int bR = 0;
  for (int t = 0; t < nT; ++t) {
    const int bW = (bR >= 1) ? bR - 1 : 2;   // (bR+2)%3
    const int base = bR * 32768;
    // first 8 reads: A-frags 0..3 + all B-frags
#pragma unroll
    for (int m_ = 0; m_ < 4; ++m_)
      am[m_] = *(const bf16x8*)(lds + base + (arow + m_ * 16) * 64 + ck);
#pragma unroll
    for (int n_ = 0; n_ < 4; ++n_)
      bfr[n_] = *(const bf16x8*)(lds + base + 16384 + (brow + n_ * 16) * 64 + ck);
    // last 4 reads: A-frags 4..7
#pragma unroll
    for (int m_ = 4; m_ < 8; ++m_)
      am[m_] = *(const bf16x8*)(lds + base + (arow + m_ * 16) * 64 + ck);
    // stage tile t+2 into freed buffer
    STG((t + 2) & tmask, bW);
    // first half compute once first 8 reads land
    asm volatile("s_waitcnt lgkmcnt(4)" ::: "memory");
    __builtin_amdgcn_sched_barrier(0);
    MM(0);
    asm volatile("s_waitcnt lgkmcnt(0)" ::: "memory");
    __builtin_amdgcn_sched_barrier(0);
    MM(1);
    // gate: tile t+1 resident (4 oldest of <=8 outstanding)
    asm volatile("s_waitcnt vmcnt(4)" ::: "memory");
    __builtin_amdgcn_sched_barrier(0);
    __builtin_amdgcn_s_barrier();
    bR = (bR == 2) ? 0 : bR + 1;
  }
  asm volatile("s_waitcnt vmcnt(0)" ::: "memory");

  // epilogue: n innermost -> 64B-line writes complete within 4 consecutive stores
  float bv[4];
#pragma unroll
  for (int n = 0; n < 4; ++n) bv[n] = bias[bn + wn * 64 + n * 16 + (lane & 15)];
  u16* Cb = (u16*)C;
  float* Cf = (float*)C;
#pragma unroll
  for (int m = 0; m < 8; ++m) {
#pragma unroll
    for (int q = 0; q < 4; ++q) {
      const long row = bm + wm * 128 + m * 16 + (lane >> 4) * 4 + q;
      const long basei = row * N + bn + wn * 64 + (lane & 15);
#pragma unroll
      for (int n = 0; n < 4; ++n) {
        float v = acc[m][n][q] + bv[n];
        if (RELU) v = fmaxf(v, 0.f);
        if (OUT_BF16) Cb[basei + n * 16] = f2bf(v);
        else          Cf[basei + n * 16] = v;
      }
    }
  }
#undef STG
#undef MM
}

// ---------------- V transpose: qkv V-block -> vt[g][h][c(64)][n(512)] ----------------
__global__ __launch_bounds__(256) void k_transpose_v(const u16* __restrict__ qkv,
                                                     u16* __restrict__ vt) {
  const int gh = blockIdx.x, g = gh >> 4, h = gh & 15;
  const int tid = threadIdx.x;
  __shared__ __align__(16) u16 tile[4096]; // [n(64)][c(64)] chunk-swizzled
  for (int nt = 0; nt < 8; ++nt) {
    const int n0 = nt * 64;
#pragma unroll
    for (int c = 0; c < 2; ++c) {
      const int ch = tid * 2 + c;           // 0..511
      const int n = ch >> 3;                // 0..63
      const int cc = ch & 7;                // logical 8-elem chunk in c-dim
      const uint4 v = *reinterpret_cast<const uint4*>(
          qkv + (long)(g * 512 + n0 + n) * 3072 + 2048 + h * 64 + cc * 8);
      const int phys = cc ^ (n & 7) ^ (n >> 3);
      *reinterpret_cast<uint4*>(tile + n * 64 + phys * 8) = v;
    }
    __syncthreads();
#pragma unroll
    for (int c = 0; c < 2; ++c) {
      const int ch = tid * 2 + c;
      const int crow = ch >> 3;             // head-col index 0..63
      const int noff = (ch & 7) * 8;
      union { u16 s[8]; uint4 u; } val;
#pragma unroll
      for (int i = 0; i < 8; ++i) {
        const int n = noff + i;
        const int phys = (crow >> 3) ^ (n & 7) ^ (n >> 3);
        val.s[i] = tile[n * 64 + phys * 8 + (crow & 7)];
      }
      *reinterpret_cast<uint4*>(vt + (long)(gh * 64 + crow) * 512 + n0 + noff) = val.u;
    }
    __syncthreads();
  }
}

// ---------------- fused attention ----------------
// grid: (8 q-blocks, 16 heads, 32 graphs), 256 threads (4 waves x 16 Q rows)
// Double-buffered K/V (2x16KB), ONE barrier/iter: {vmcnt(0); barrier; stage(t+1);
// compute(t)}. K source advances kv0 ROWS (x6144 B/row); V source advances kv0
// COLUMNS (x2 B/elem)  <- round-6 bug was x128 here.
__global__ __launch_bounds__(256) void k_attn(const u16* __restrict__ qkv,
                                              const u16* __restrict__ vt,
                                              u16* __restrict__ out) {
  __shared__ __align__(16) char KV[2][16384];   // per buf: K [64][128B] swz | V [64][128B] swz
  __shared__ __align__(16) char Ps[4][2048];    // per-wave P [16][128B], swizzled
  const int tid = threadIdx.x, lane = tid & 63, wid = tid >> 6;
  const int qb = blockIdx.x, h = blockIdx.y, g = blockIdx.z;
  const int gh = g * 16 + h;
  const long grow0 = (long)g * 512;
  const char* qbase = (const char*)qkv;
  const char* vbase = (const char*)vt;

  // Q fragments (row = lane&15 of this wave's 16-row strip)
  const long qrow = qb * 64 + wid * 16 + (lane & 15);
  bf16x8 qf[2];
#pragma unroll
  for (int kf = 0; kf < 2; ++kf) {
    const long go = (((grow0 + qrow) * 3072) + h * 64 + kf * 32 + (lane >> 4) * 8) * 2;
    qf[kf] = *reinterpret_cast<const bf16x8*>(qbase + go);
  }

  // staging geometry (source-side XOR swizzle, linear LDS dest)
  long gKb[2], gVb[2];
  unsigned dK[2];
#pragma unroll
  for (int c = 0; c < 2; ++c) {
    const int o = wid * 2048 + c * 1024 + lane * 16;
    const int row = o >> 7;
    const int lch = ((o >> 4) & 7) ^ (row & 7);
    gKb[c] = (((grow0 + row) * 3072) + 1024 + h * 64 + lch * 8) * 2;
    gVb[c] = (((long)(gh * 64 + row)) * 512 + lch * 8) * 2;
    dK[c] = (unsigned)__builtin_amdgcn_readfirstlane(wid * 2048 + c * 1024);
  }

#define STGKV(kv0_, buf_) do { \
  _Pragma("unroll") for (int c_ = 0; c_ < 2; ++c_) { \
    __builtin_amdgcn_global_load_lds(AS1C(qbase + gKb[c_] + (long)(kv0_) * 6144), \
        AS3C(&KV[buf_][0] + dK[c_]), 16, 0, 0); \
    __builtin_amdgcn_global_load_lds(AS1C(vbase + gVb[c_] + (long)(kv0_) * 2), \
        AS3C(&KV[buf_][0] + 8192 + dK[c_]), 16, 0, 0); \
  } } while (0)

  f32x4 oacc[4];
#pragma unroll
  for (int i = 0; i < 4; i++) oacc[i] = 0.f;
  float mrun[4], lrun[4];
#pragma unroll
  for (int q = 0; q < 4; q++) { mrun[q] = -3.0e38f; lrun[q] = 0.f; }

  STGKV(0, 0);   // prologue

  for (int it = 0; it < 8; ++it) {
    const int buf = it & 1;
    asm volatile("s_waitcnt vmcnt(0)" ::: "memory");
    __builtin_amdgcn_sched_barrier(0);
    __builtin_amdgcn_s_barrier();
    __builtin_amdgcn_sched_barrier(0);
    if (it < 7) STGKV(it * 64 + 64, buf ^ 1);
    const char* Kb = &KV[buf][0];
    const char* Vb = &KV[buf][0] + 8192;

    // S = Q K^T / 8  (4 tiles of 16 kv cols)
    f32x4 s[4];
#pragma unroll
    for (int nt = 0; nt < 4; ++nt) {
      const int krow = nt * 16 + (lane & 15);
      const int sw = krow & 7;
      const bf16x8 k0 = *reinterpret_cast<const bf16x8*>(Kb + krow * 128 + (((lane >> 4)) ^ sw) * 16);
      const bf16x8 k1 = *reinterpret_cast<const bf16x8*>(Kb + krow * 128 + (((lane >> 4) + 4) ^ sw) * 16);
      f32x4 t = 0.f;
      t = __builtin_amdgcn_mfma_f32_16x16x32_bf16(qf[0], k0, t, 0, 0, 0);
      t = __builtin_amdgcn_mfma_f32_16x16x32_bf16(qf[1], k1, t, 0, 0, 0);
#pragma unroll
      for (int q = 0; q < 4; q++) t[q] *= 0.125f;
      s[nt] = t;
    }

    // online softmax update (rows owned: (lane>>4)*4+q; cols across 16 lanes)
    float tmax[4];
#pragma unroll
    for (int q = 0; q < 4; q++)
      tmax[q] = fmaxf(fmaxf(s[0][q], s[1][q]), fmaxf(s[2][q], s[3][q]));
#pragma unroll
    for (int d = 1; d < 16; d <<= 1)
#pragma unroll
      for (int q = 0; q < 4; q++) tmax[q] = fmaxf(tmax[q], __shfl_xor(tmax[q], d));
    float sf[4];
#pragma unroll
    for (int q = 0; q < 4; q++) {
      const float mn = fmaxf(mrun[q], tmax[q]);
      sf[q] = __expf(mrun[q] - mn);
      mrun[q] = mn;
    }
    float rs[4] = {0.f, 0.f, 0.f, 0.f};
#pragma unroll
    for (int nt = 0; nt < 4; nt++)
#pragma unroll
      for (int q = 0; q < 4; q++) {
        const float p = __expf(s[nt][q] - mrun[q]);
        s[nt][q] = p;
        rs[q] += p;
      }
#pragma unroll
    for (int d = 1; d < 16; d <<= 1)
#pragma unroll
      for (int q = 0; q < 4; q++) rs[q] += __shfl_xor(rs[q], d);
#pragma unroll
    for (int q = 0; q < 4; q++) lrun[q] = lrun[q] * sf[q] + rs[q];
#pragma unroll
    for (int i = 0; i < 4; i++)
#pragma unroll
      for (int q = 0; q < 4; q++) oacc[i][q] *= sf[q];

    // P (bf16) -> per-wave LDS, swizzled (within-wave dep only; no barrier needed)
    char* pw = Ps[wid];
#pragma unroll
    for (int nt = 0; nt < 4; nt++) {
      const int cc = nt * 16 + (lane & 15);
#pragma unroll
      for (int q = 0; q < 4; q++) {
        const int r = (lane >> 4) * 4 + q;
        const int phys = (cc >> 3) ^ (r & 7);
        *(u16*)(pw + r * 128 + phys * 16 + (cc & 7) * 2) = f2bf(s[nt][q]);
      }
    }

    // O += P V
#pragma unroll
    for (int kf = 0; kf < 2; ++kf) {
      const int prow = lane & 15;
      const bf16x8 pa = *reinterpret_cast<const bf16x8*>(
          pw + prow * 128 + ((kf * 4 + (lane >> 4)) ^ (prow & 7)) * 16);
#pragma unroll
      for (int ot = 0; ot < 4; ++ot) {
        const int vr = ot * 16 + (lane & 15);
        const bf16x8 vb = *reinterpret_cast<const bf16x8*>(
            Vb + vr * 128 + ((kf * 4 + (lane >> 4)) ^ (vr & 7)) * 16);
        oacc[ot] = __builtin_amdgcn_mfma_f32_16x16x32_bf16(pa, vb, oacc[ot], 0, 0, 0);
      }
    }
  }
#undef STGKV

  // epilogue: O / l -> bf16
#pragma unroll
  for (int ot = 0; ot < 4; ++ot) {
    const int col = h * 64 + ot * 16 + (lane & 15);
#pragma unroll
    for (int q = 0; q < 4; q++) {
      const long r = grow0 + qb * 64 + wid * 16 + (lane >> 4) * 4 + q;
      out[r * 1024 + col] = f2bf(oacc[ot][q] / lrun[q]);
    }
  }
}

// ---------------- residual + layernorm ----------------
template<bool EMIT_BF16>
__global__ __launch_bounds__(256) void k_ln(const float* __restrict__ A,
                                            const float* __restrict__ Bz,
                                            const float* __restrict__ gam,
                                            const float* __restrict__ bet,
                                            float* __restrict__ out_f,
                                            u16* __restrict__ out_b) {
  const int row = blockIdx.x;
  const int tid = threadIdx.x;
  const long base = (long)row * 1024;
  const float4 a = reinterpret_cast<const float4*>(A + base)[tid];
  const float4 b = reinterpret_cast<const float4*>(Bz + base)[tid];
  const float x0 = a.x + b.x, x1 = a.y + b.y, x2 = a.z + b.z, x3 = a.w + b.w;
  float s1 = x0 + x1 + x2 + x3;
  float s2 = x0 * x0 + x1 * x1 + x2 * x2 + x3 * x3;
#pragma unroll
  for (int d = 1; d < 64; d <<= 1) { s1 += __shfl_xor(s1, d); s2 += __shfl_xor(s2, d); }
  __shared__ float red[8];
  const int wid = tid >> 6, lane = tid & 63;
  if (lane == 0) { red[wid] = s1; red[4 + wid] = s2; }
  __syncthreads();
  s1 = red[0] + red[1] + red[2] + red[3];
  s2 = red[4] + red[5] + red[6] + red[7];
  const float mu = s1 * (1.f / 1024.f);
  const float var = s2 * (1.f / 1024.f) - mu * mu;
  const float rstd = rsqrtf(var + 1e-5f);
  const float4 gv = reinterpret_cast<const float4*>(gam)[tid];
  const float4 bv = reinterpret_cast<const float4*>(bet)[tid];
  float4 y;
  y.x = (x0 - mu) * rstd * gv.x + bv.x;
  y.y = (x1 - mu) * rstd * gv.y + bv.y;
  y.z = (x2 - mu) * rstd * gv.z + bv.z;
  y.w = (x3 - mu) * rstd * gv.w + bv.w;
  reinterpret_cast<float4*>(out_f + base)[tid] = y;
  if (EMIT_BF16) {
    ushort4 o;
    o.x = f2bf(y.x); o.y = f2bf(y.y); o.z = f2bf(y.z); o.w = f2bf(y.w);
    reinterpret_cast<ushort4*>(out_b + base)[tid] = o;
  }
}

// ---------------- launcher ----------------
extern "C" void kernel_launch(void* const* d_in, const int* in_sizes, int n_in,
                              void* d_out, int out_size, void* d_ws, size_t ws_size,
                              hipStream_t stream) {
  const float* h    = (const float*)d_in[0];
  const float* w_in = (const float*)d_in[1];
  const float* b_in = (const float*)d_in[2];
  const float* w_o  = (const float*)d_in[3];
  const float* b_o  = (const float*)d_in[4];
  const float* ln1g = (const float*)d_in[5];
  const float* ln1b = (const float*)d_in[6];
  const float* ln2g = (const float*)d_in[7];
  const float* ln2b = (const float*)d_in[8];
  const float* w1   = (const float*)d_in[9];
  const float* b1   = (const float*)d_in[10];
  const float* w2   = (const float*)d_in[11];
  const float* b2   = (const float*)d_in[12];

  const size_t WS_NEED = 184549376;
  if (ws_size < WS_NEED) {
    hipMemsetAsync(d_out, 0, (size_t)out_size * 4, stream);
    return;
  }

  char* W = (char*)d_ws;
  u16* h_bf     = (u16*)(W + 0);            // 33554432 B
  u16* w_in_bf  = (u16*)(W + 33554432);     // 6291456 B
  u16* w_out_bf = (u16*)(W + 39845888);     // 2097152 B
  u16* w1_bf    = (u16*)(W + 41943040);     // 4194304 B
  u16* w2_bf    = (u16*)(W + 46137344);     // 4194304 B
  u16* qkv      = (u16*)(W + 50331648);     // 100663296 B (dead after attn)
  u16* vt       = (u16*)(W + 150994944);    // 33554432 B  (dead after attn)
  float* x1     = (float*)(W + 50331648);   // 67108864 B (reuses qkv[0:67MB))
  u16* f1       = (u16*)(W + 117440512);    // 67108864 B (reuses qkv tail + vt)
  u16* attn_bf  = h_bf;
  u16* x1_bf    = h_bf;
  float* o32    = (float*)d_out;
  float* f2     = (float*)d_out;

  // bf16 conversions (single launch)
  k_f2bf5<<<dim3(24576), 256, 0, stream>>>(h, h_bf, w_in, w_in_bf, w_o, w_out_bf,
                                           w1, w1_bf, w2, w2_bf);

  // qkv = h @ w_in^T + b_in   [16384, 3072] bf16   grid 64*12=768
  k_gemm256<true, false><<<dim3(768), 512, 0, stream>>>(h_bf, w_in_bf, b_in, (void*)qkv, 16384, 3072, 1024);
  // V transpose for attention B-operand
  k_transpose_v<<<dim3(512), 256, 0, stream>>>(qkv, vt);
  // fused attention -> attn_bf [16384, 1024] bf16
  k_attn<<<dim3(8, 16, 32), 256, 0, stream>>>(qkv, vt, attn_bf);
  // o = attn @ w_out^T + b_out  [16384, 1024] fp32 -> d_out   grid 64*4=256
  k_gemm256<false, false><<<dim3(256), 512, 0, stream>>>(attn_bf, w_out_bf, b_o, (void*)o32, 16384, 1024, 1024);
  // x1 = LN(h + o); also emit x1 as bf16 for FFN
  k_ln<true><<<dim3(16384), 256, 0, stream>>>(h, o32, ln1g, ln1b, x1, x1_bf);
  // f1 = relu(x1 @ w1^T + b1)  [16384, 2048] bf16   grid 64*8=512
  k_gemm256<true, true><<<dim3(512), 512, 0, stream>>>(x1_bf, w1_bf, b1, (void*)f1, 16384, 2048, 1024);
  // f2 = f1 @ w2^T + b2        [16384, 1024] fp32 -> d_out   grid 64*4=256
  k_gemm256<false, false><<<dim3(256), 512, 0, stream>>>(f1, w2_bf, b2, (void*)f2, 16384, 1024, 2048);
  // out = LN(x1 + f2)  (in-place on d_out)
  k_ln<false><<<dim3(16384), 256, 0, stream>>>(x1, f2, ln2g, ln2b, (float*)d_out, (u16*)nullptr);
}